// Round 5
// baseline (425.856 us; speedup 1.0000x reference)
//
#include <hip/hip_runtime.h>
#include <hip/hip_bf16.h>

#define NN 8192
#define DD 128

typedef __attribute__((ext_vector_type(4))) float f32x4;
typedef __attribute__((ext_vector_type(8))) short s16x8;
typedef __attribute__((ext_vector_type(4))) short s16x4;

__device__ inline short bfbits(float f) {
    // fp32 -> bf16 (RNE) bit pattern
    unsigned u = __builtin_bit_cast(unsigned, f);
    u += 0x7fffu + ((u >> 16) & 1u);
    return (short)(u >> 16);
}

__device__ inline s16x4 cvt4(f32x4 a) {
    s16x4 r;
    r[0] = bfbits(a[0]); r[1] = bfbits(a[1]); r[2] = bfbits(a[2]); r[3] = bfbits(a[3]);
    return r;
}

__device__ inline s16x8 cvt8(f32x4 a, f32x4 b) {
    s16x8 r;
    r[0] = bfbits(a[0]); r[1] = bfbits(a[1]); r[2] = bfbits(a[2]); r[3] = bfbits(a[3]);
    r[4] = bfbits(b[0]); r[5] = bfbits(b[1]); r[6] = bfbits(b[2]); r[7] = bfbits(b[3]);
    return r;
}

#define WST 132  // LDS stride (shorts) for W tile: kills 8-way bank conflicts

// ======== Kernel 1 (prep): deg blocks [0,2048) + trailing proj blocks [2048,2560) ======
// deg body and proj body are byte-identical to the proven R0 kernels, except proj's
// dinv-scale is deferred (fp32 hU out, scaled+converted by scale_kernel — both pieces
// harness-proven in round 2). deg blocks dispatch first => fill all CUs; proj's 512
// blocks trail into the holes as deg retires, hiding proj's ~10us of non-HBM work.
__global__ __launch_bounds__(256) void prep_kernel(const float* __restrict__ adj,
                                                   const float* __restrict__ x,
                                                   const float* __restrict__ w,
                                                   float* __restrict__ dinv,
                                                   float* __restrict__ hU) {
    __shared__ short lds_w[128 * WST];
    const int tid = threadIdx.x;

    if (blockIdx.x < 2048) {
        // ---- deg: 4 rows per block (exact R0 deg_kernel body) ----
        const int lane = tid & 63;
        const int row  = (blockIdx.x << 2) + (tid >> 6);
        const float* r = adj + (size_t)row * NN;

        f32x4 s = {0.f, 0.f, 0.f, 0.f};
        #pragma unroll 4
        for (int it = 0; it < 32; ++it) {
            f32x4 v = *(const f32x4*)(r + it * 256 + (lane << 2));
            s += v;
        }
        float sum = s[0] + s[1] + s[2] + s[3];
        #pragma unroll
        for (int off = 32; off; off >>= 1) sum += __shfl_xor(sum, off, 64);
        if (lane == 0) dinv[row] = (sum > 0.f) ? rsqrtf(sum) : 0.f;
    } else {
        // ---- proj: rows [pb*16, pb*16+16), UNscaled, fp32 fragment-order out ----
        const int pb   = blockIdx.x - 2048;        // 0..511
        const int lane = tid & 63;
        const int wave = tid >> 6;
        const int j0   = pb << 4;
        const int n0   = wave << 5;
        const int r    = lane & 15;
        const int q    = lane >> 4;

        #pragma unroll
        for (int i = 0; i < 16; ++i) {
            int gi = i * 256 + tid;
            int k  = gi >> 5;
            int n4 = (gi & 31) << 2;
            f32x4 v = *(const f32x4*)(w + (size_t)k * DD + n4);
            *(s16x4*)&lds_w[k * WST + n4] = cvt4(v);
        }
        __syncthreads();

        const float* xp = x + (size_t)(j0 + r) * DD + (q << 3);
        f32x4 acc0 = {0.f, 0.f, 0.f, 0.f};
        f32x4 acc1 = {0.f, 0.f, 0.f, 0.f};

        #pragma unroll
        for (int k = 0; k < DD; k += 32) {
            f32x4 a0 = *(const f32x4*)(xp + k);
            f32x4 a1 = *(const f32x4*)(xp + k + 4);
            s16x8 af = cvt8(a0, a1);
            const int kb = k + (q << 3);
            s16x8 b0, b1;
            #pragma unroll
            for (int jj = 0; jj < 8; ++jj) {
                b0[jj] = lds_w[(kb + jj) * WST + n0 + r];
                b1[jj] = lds_w[(kb + jj) * WST + n0 + 16 + r];
            }
            acc0 = __builtin_amdgcn_mfma_f32_16x16x32_bf16(af, b0, acc0, 0, 0, 0);
            acc1 = __builtin_amdgcn_mfma_f32_16x16x32_bf16(af, b1, acc1, 0, 0, 0);
        }

        // C/D: col = lane&15 (n), row = q*4+rr (j). fp32 scatter into fragment order.
        #pragma unroll
        for (int rr = 0; rr < 4; ++rr) {
            const int j  = j0 + (q << 2) + rr;
            const int kg = j >> 5, qp = (j >> 3) & 3, jj = j & 7;
            #pragma unroll
            for (int half = 0; half < 2; ++half) {
                const int n = n0 + half * 16 + r;
                const int f = n >> 4;
                const int lanep = qp * 16 + (n & 15);
                hU[(((size_t)((f << 8) | kg) << 6) | lanep) * 8 + jj] =
                    (half ? acc1[rr] : acc0[rr]);
            }
        }
    }
}

// ======== Kernel 2 (scale): h2f = bf16(dinv[j] * hU) — harness-proven in round 2 ======
__global__ __launch_bounds__(256) void scale_kernel(const float* __restrict__ hU,
                                                    const float* __restrict__ dinv,
                                                    unsigned short* __restrict__ h2f) {
    const int s  = blockIdx.x * 256 + threadIdx.x;   // slot id, 131072 total
    const int kg = (s >> 6) & 255;
    const int qp = (s >> 4) & 3;
    const int j0 = (kg << 5) + (qp << 3);            // 8 consecutive j per slot
    f32x4 a  = *(const f32x4*)(hU + (size_t)s * 8);
    f32x4 b  = *(const f32x4*)(hU + (size_t)s * 8 + 4);
    f32x4 d0 = *(const f32x4*)(dinv + j0);
    f32x4 d1 = *(const f32x4*)(dinv + j0 + 4);
    s16x8 o;
    o[0] = bfbits(a[0] * d0[0]); o[1] = bfbits(a[1] * d0[1]);
    o[2] = bfbits(a[2] * d0[2]); o[3] = bfbits(a[3] * d0[3]);
    o[4] = bfbits(b[0] * d1[0]); o[5] = bfbits(b[1] * d1[1]);
    o[6] = bfbits(b[2] * d1[2]); o[7] = bfbits(b[3] * d1[3]);
    *(s16x8*)(h2f + (size_t)s * 8) = o;
}

// ======== Kernel 3 (agg32): BM=32 B-register reuse — BYTE-IDENTICAL to round 4 ========
template <int KSPLIT>
__global__ __launch_bounds__(256, 4) void agg32_kernel(const float* __restrict__ adj,
                                                       const unsigned short* __restrict__ h2f,
                                                       float* __restrict__ dst) {
    constexpr int KS    = NN / KSPLIT;
    constexpr int TILES = KS / 128;
    __shared__ short lds_a[2][2][16 * 16 * 8];  // [buf][subtile(16 rows)][slot*8 shorts]

    const int tid  = threadIdx.x;
    const int lane = tid & 63;
    const int wave = tid >> 6;
    const int r    = lane & 15;
    const int q    = lane >> 4;
    const int m0   = blockIdx.x << 5;
    const int k0   = blockIdx.y * KS;

    const int row0 = tid >> 5;              // 0..7
    const int off0 = (tid & 31) << 2;
    const int cd   = (tid & 31) >> 1;       // dest 16B chunk (8 bf16)
    const int hh   = tid & 1;               // which half of the chunk
    const int so0  = ((row0 << 4) + (cd ^ row0)) * 8 + hh * 4;
    const int so1  = (((8 + row0) << 4) + (cd ^ (8 + row0))) * 8 + hh * 4;

    const float* ap0 = adj + (size_t)(m0 + row0)      * NN + k0 + off0;
    const float* ap1 = adj + (size_t)(m0 + 8 + row0)  * NN + k0 + off0;
    const float* ap2 = adj + (size_t)(m0 + 16 + row0) * NN + k0 + off0;
    const float* ap3 = adj + (size_t)(m0 + 24 + row0) * NN + k0 + off0;

    const unsigned short* bb0 = h2f + (((size_t)(wave * 2)     * 256 + (k0 >> 5)) * 64 + lane) * 8;
    const unsigned short* bb1 = h2f + (((size_t)(wave * 2 + 1) * 256 + (k0 >> 5)) * 64 + lane) * 8;

    f32x4 acc00 = {0.f, 0.f, 0.f, 0.f};
    f32x4 acc01 = {0.f, 0.f, 0.f, 0.f};
    f32x4 acc10 = {0.f, 0.f, 0.f, 0.f};
    f32x4 acc11 = {0.f, 0.f, 0.f, 0.f};

    {
        f32x4 v0 = *(const f32x4*)(ap0);
        f32x4 v1 = *(const f32x4*)(ap1);
        f32x4 v2 = *(const f32x4*)(ap2);
        f32x4 v3 = *(const f32x4*)(ap3);
        *(s16x4*)&lds_a[0][0][so0] = cvt4(v0);
        *(s16x4*)&lds_a[0][0][so1] = cvt4(v1);
        *(s16x4*)&lds_a[0][1][so0] = cvt4(v2);
        *(s16x4*)&lds_a[0][1][so1] = cvt4(v3);
    }
    __syncthreads();

    for (int t = 0; t < TILES; ++t) {
        const short* lc0 = lds_a[t & 1][0];
        const short* lc1 = lds_a[t & 1][1];

        s16x8 br0[4], br1[4];
        #pragma unroll
        for (int s = 0; s < 4; ++s) {
            br0[s] = *(const s16x8*)(bb0 + (size_t)(t * 4 + s) * 512);
            br1[s] = *(const s16x8*)(bb1 + (size_t)(t * 4 + s) * 512);
        }
        f32x4 v0, v1, v2, v3;
        if (t + 1 < TILES) {
            v0 = *(const f32x4*)(ap0 + (t + 1) * 128);
            v1 = *(const f32x4*)(ap1 + (t + 1) * 128);
            v2 = *(const f32x4*)(ap2 + (t + 1) * 128);
            v3 = *(const f32x4*)(ap3 + (t + 1) * 128);
        }
        #pragma unroll
        for (int s = 0; s < 4; ++s) {
            const int slot = (r << 4) + (((s << 2) + q) ^ r);
            s16x8 afA = *(const s16x8*)(lc0 + slot * 8);
            s16x8 afB = *(const s16x8*)(lc1 + slot * 8);
            acc00 = __builtin_amdgcn_mfma_f32_16x16x32_bf16(afA, br0[s], acc00, 0, 0, 0);
            acc01 = __builtin_amdgcn_mfma_f32_16x16x32_bf16(afA, br1[s], acc01, 0, 0, 0);
            acc10 = __builtin_amdgcn_mfma_f32_16x16x32_bf16(afB, br0[s], acc10, 0, 0, 0);
            acc11 = __builtin_amdgcn_mfma_f32_16x16x32_bf16(afB, br1[s], acc11, 0, 0, 0);
        }
        if (t + 1 < TILES) {
            short* ln0 = (short*)lds_a[(t + 1) & 1][0];
            short* ln1 = (short*)lds_a[(t + 1) & 1][1];
            *(s16x4*)(ln0 + so0) = cvt4(v0);
            *(s16x4*)(ln0 + so1) = cvt4(v1);
            *(s16x4*)(ln1 + so0) = cvt4(v2);
            *(s16x4*)(ln1 + so1) = cvt4(v3);
        }
        __syncthreads();
    }

    float* p = dst + (size_t)blockIdx.y * NN * DD;
    #pragma unroll
    for (int rr = 0; rr < 4; ++rr) {
        const int mA = m0 + (q << 2) + rr;
        const int mB = mA + 16;
        const int n  = (wave << 5) + r;
        p[(size_t)mA * DD + n]      = acc00[rr];
        p[(size_t)mA * DD + n + 16] = acc01[rr];
        p[(size_t)mB * DD + n]      = acc10[rr];
        p[(size_t)mB * DD + n + 16] = acc11[rr];
    }
}

// ======== Kernel 4: out = dinv[m]*(p0+p1+p2+p3) + bias (round-4 proven) ===============
__global__ __launch_bounds__(256) void reduce4_kernel(const float* __restrict__ part,
                                                      const float* __restrict__ dinv,
                                                      const float* __restrict__ bias,
                                                      float* __restrict__ out) {
    const int idx = blockIdx.x * 256 + threadIdx.x;   // f32x4 index, NN*DD/4 total
    const f32x4 a = ((const f32x4*)part)[idx];
    const f32x4 b = ((const f32x4*)part)[idx + NN * DD / 4];
    const f32x4 c = ((const f32x4*)part)[idx + 2 * (NN * DD / 4)];
    const f32x4 d = ((const f32x4*)part)[idx + 3 * (NN * DD / 4)];
    const float dv = dinv[idx >> 5];
    const f32x4 bi = *(const f32x4*)(bias + ((idx & 31) << 2));
    f32x4 s = (a + b) + (c + d);
    f32x4 o;
    o[0] = s[0] * dv + bi[0]; o[1] = s[1] * dv + bi[1];
    o[2] = s[2] * dv + bi[2]; o[3] = s[3] * dv + bi[3];
    ((f32x4*)out)[idx] = o;
}

// ======== FALLBACK kernels (proven R0/R4 path for smaller workspaces) =================
__global__ __launch_bounds__(256) void deg_kernel(const float* __restrict__ adj,
                                                  float* __restrict__ dinv) {
    const int lane = threadIdx.x & 63;
    const int row  = (blockIdx.x << 2) + (threadIdx.x >> 6);
    const float* r = adj + (size_t)row * NN;
    f32x4 s = {0.f, 0.f, 0.f, 0.f};
    #pragma unroll 4
    for (int it = 0; it < 32; ++it) {
        f32x4 v = *(const f32x4*)(r + it * 256 + (lane << 2));
        s += v;
    }
    float sum = s[0] + s[1] + s[2] + s[3];
    #pragma unroll
    for (int off = 32; off; off >>= 1) sum += __shfl_xor(sum, off, 64);
    if (lane == 0) dinv[row] = (sum > 0.f) ? rsqrtf(sum) : 0.f;
}

__global__ __launch_bounds__(256) void proj_kernel(const float* __restrict__ x,
                                                   const float* __restrict__ w,
                                                   const float* __restrict__ dinv,
                                                   unsigned short* __restrict__ h2f) {
    __shared__ short lds_w[128 * WST];
    const int tid  = threadIdx.x;
    const int lane = tid & 63;
    const int wave = tid >> 6;
    const int j0   = blockIdx.x << 4;
    const int n0   = wave << 5;
    const int r    = lane & 15;
    const int q    = lane >> 4;
    #pragma unroll
    for (int i = 0; i < 16; ++i) {
        int gi = i * 256 + tid;
        int k  = gi >> 5;
        int n4 = (gi & 31) << 2;
        f32x4 v = *(const f32x4*)(w + (size_t)k * DD + n4);
        *(s16x4*)&lds_w[k * WST + n4] = cvt4(v);
    }
    __syncthreads();
    const float* xp = x + (size_t)(j0 + r) * DD + (q << 3);
    f32x4 acc0 = {0.f, 0.f, 0.f, 0.f};
    f32x4 acc1 = {0.f, 0.f, 0.f, 0.f};
    #pragma unroll
    for (int k = 0; k < DD; k += 32) {
        f32x4 a0 = *(const f32x4*)(xp + k);
        f32x4 a1 = *(const f32x4*)(xp + k + 4);
        s16x8 af = cvt8(a0, a1);
        const int kb = k + (q << 3);
        s16x8 b0, b1;
        #pragma unroll
        for (int jj = 0; jj < 8; ++jj) {
            b0[jj] = lds_w[(kb + jj) * WST + n0 + r];
            b1[jj] = lds_w[(kb + jj) * WST + n0 + 16 + r];
        }
        acc0 = __builtin_amdgcn_mfma_f32_16x16x32_bf16(af, b0, acc0, 0, 0, 0);
        acc1 = __builtin_amdgcn_mfma_f32_16x16x32_bf16(af, b1, acc1, 0, 0, 0);
    }
    #pragma unroll
    for (int rr = 0; rr < 4; ++rr) {
        const int j = j0 + (q << 2) + rr;
        const float dv = dinv[j];
        const int kg = j >> 5, qp = (j >> 3) & 3, jj = j & 7;
        #pragma unroll
        for (int half = 0; half < 2; ++half) {
            const int n = n0 + half * 16 + r;
            const int f = n >> 4;
            const int lanep = qp * 16 + (n & 15);
            const float v = (half ? acc1[rr] : acc0[rr]) * dv;
            h2f[((((size_t)f << 8) + kg) << 6 | lanep) * 8 + jj] = (unsigned short)bfbits(v);
        }
    }
}

template <int KSPLIT>
__global__ __launch_bounds__(256, 4) void agg_kernel(const float* __restrict__ adj,
                                                     const unsigned short* __restrict__ h2f,
                                                     const float* __restrict__ dinv,
                                                     const float* __restrict__ bias,
                                                     float* __restrict__ dst) {
    constexpr int KS    = NN / KSPLIT;
    constexpr int TILES = KS / 128;
    __shared__ short lds_a[2][16 * 16 * 8];
    const int tid  = threadIdx.x;
    const int lane = tid & 63;
    const int wave = tid >> 6;
    const int r    = lane & 15;
    const int q    = lane >> 4;
    const int m0   = blockIdx.x << 4;
    const int k0   = blockIdx.y * KS;
    const int row0 = tid >> 5;
    const int off0 = (tid & 31) << 2;
    const int cd   = (tid & 31) >> 1;
    const int hh   = tid & 1;
    const int so0  = ((row0 << 4) + (cd ^ row0)) * 8 + hh * 4;
    const int so1  = (((8 + row0) << 4) + (cd ^ (8 + row0))) * 8 + hh * 4;
    const float* ap0 = adj + (size_t)(m0 + row0) * NN + k0 + off0;
    const float* ap1 = adj + (size_t)(m0 + 8 + row0) * NN + k0 + off0;
    const unsigned short* bb0 = h2f + (((size_t)(wave * 2)     * 256 + (k0 >> 5)) * 64 + lane) * 8;
    const unsigned short* bb1 = h2f + (((size_t)(wave * 2 + 1) * 256 + (k0 >> 5)) * 64 + lane) * 8;
    f32x4 acc0 = {0.f, 0.f, 0.f, 0.f};
    f32x4 acc1 = {0.f, 0.f, 0.f, 0.f};
    {
        f32x4 v0 = *(const f32x4*)(ap0);
        f32x4 v1 = *(const f32x4*)(ap1);
        *(s16x4*)&lds_a[0][so0] = cvt4(v0);
        *(s16x4*)&lds_a[0][so1] = cvt4(v1);
    }
    __syncthreads();
    for (int t = 0; t < TILES; ++t) {
        const short* lcur = lds_a[t & 1];
        short* lnxt = (short*)lds_a[(t + 1) & 1];
        s16x8 br0[4], br1[4];
        #pragma unroll
        for (int s = 0; s < 4; ++s) {
            br0[s] = *(const s16x8*)(bb0 + (size_t)(t * 4 + s) * 512);
            br1[s] = *(const s16x8*)(bb1 + (size_t)(t * 4 + s) * 512);
        }
        f32x4 v0, v1;
        if (t + 1 < TILES) {
            v0 = *(const f32x4*)(ap0 + (t + 1) * 128);
            v1 = *(const f32x4*)(ap1 + (t + 1) * 128);
        }
        #pragma unroll
        for (int s = 0; s < 4; ++s) {
            const int slot = (r << 4) + (((s << 2) + q) ^ r);
            s16x8 af = *(const s16x8*)(lcur + slot * 8);
            acc0 = __builtin_amdgcn_mfma_f32_16x16x32_bf16(af, br0[s], acc0, 0, 0, 0);
            acc1 = __builtin_amdgcn_mfma_f32_16x16x32_bf16(af, br1[s], acc1, 0, 0, 0);
        }
        if (t + 1 < TILES) {
            *(s16x4*)(lnxt + so0) = cvt4(v0);
            *(s16x4*)(lnxt + so1) = cvt4(v1);
        }
        __syncthreads();
    }
    #pragma unroll
    for (int rr = 0; rr < 4; ++rr) {
        const int m = m0 + (q << 2) + rr;
        const int n = (wave << 5) + r;
        if (KSPLIT == 1) {
            const float dv = dinv[m];
            dst[(size_t)m * DD + n]      = acc0[rr] * dv + bias[n];
            dst[(size_t)m * DD + n + 16] = acc1[rr] * dv + bias[n + 16];
        } else {
            float* p = dst + (size_t)blockIdx.y * NN * DD;
            p[(size_t)m * DD + n]      = acc0[rr];
            p[(size_t)m * DD + n + 16] = acc1[rr];
        }
    }
}

__global__ __launch_bounds__(256) void reduce_kernel(const float* __restrict__ part,
                                                     const float* __restrict__ dinv,
                                                     const float* __restrict__ bias,
                                                     float* __restrict__ out) {
    const int idx = blockIdx.x * 256 + threadIdx.x;
    const f32x4 a = ((const f32x4*)part)[idx];
    const f32x4 b = ((const f32x4*)part)[idx + NN * DD / 4];
    const float dv = dinv[idx >> 5];
    const f32x4 bi = *(const f32x4*)(bias + ((idx & 31) << 2));
    f32x4 s = a + b;
    f32x4 o;
    o[0] = s[0] * dv + bi[0]; o[1] = s[1] * dv + bi[1];
    o[2] = s[2] * dv + bi[2]; o[3] = s[3] * dv + bi[3];
    ((f32x4*)out)[idx] = o;
}

extern "C" void kernel_launch(void* const* d_in, const int* in_sizes, int n_in,
                              void* d_out, int out_size, void* d_ws, size_t ws_size,
                              hipStream_t stream) {
    const float* x    = (const float*)d_in[0];   // [8192][128]
    const float* adj  = (const float*)d_in[1];   // [8192][8192]
    const float* w    = (const float*)d_in[2];   // [128][128]
    const float* bias = (const float*)d_in[3];   // [128]
    float* out = (float*)d_out;                  // [8192][128]

    // ws layout: dinv 32KB | h2f 2MB | hU 4MB | part up to 4 x 4MB
    float* dinv         = (float*)d_ws;
    unsigned short* h2f = (unsigned short*)((char*)d_ws + 32 * 1024);
    float* hU           = (float*)((char*)d_ws + 32 * 1024 + 2 * 1024 * 1024);
    float* part         = (float*)((char*)d_ws + 32 * 1024 + 6 * 1024 * 1024);
    const size_t base_f = 32 * 1024 + 6 * 1024 * 1024;                      // with hU
    const size_t need_fused = base_f + (size_t)4 * NN * DD * sizeof(float);
    const size_t base_s = 32 * 1024 + 2 * 1024 * 1024;                      // no hU
    const size_t need4  = base_s + (size_t)4 * NN * DD * sizeof(float);
    const size_t need2  = base_s + (size_t)2 * NN * DD * sizeof(float);

    if (ws_size >= need_fused) {
        prep_kernel<<<2560, 256, 0, stream>>>(adj, x, w, dinv, hU);
        scale_kernel<<<512, 256, 0, stream>>>(hU, dinv, h2f);
        agg32_kernel<4><<<dim3(NN / 32, 4), 256, 0, stream>>>(adj, h2f, part);
        reduce4_kernel<<<NN * DD / 4 / 256, 256, 0, stream>>>(part, dinv, bias, out);
    } else if (ws_size >= need4) {
        float* part_s = (float*)((char*)d_ws + base_s);
        deg_kernel<<<NN / 4, 256, 0, stream>>>(adj, dinv);
        proj_kernel<<<NN / 16, 256, 0, stream>>>(x, w, dinv, h2f);
        agg32_kernel<4><<<dim3(NN / 32, 4), 256, 0, stream>>>(adj, h2f, part_s);
        reduce4_kernel<<<NN * DD / 4 / 256, 256, 0, stream>>>(part_s, dinv, bias, out);
    } else if (ws_size >= need2) {
        float* part_s = (float*)((char*)d_ws + base_s);
        deg_kernel<<<NN / 4, 256, 0, stream>>>(adj, dinv);
        proj_kernel<<<NN / 16, 256, 0, stream>>>(x, w, dinv, h2f);
        agg_kernel<2><<<dim3(NN / 16, 2), 256, 0, stream>>>(adj, h2f, dinv, bias, part_s);
        reduce_kernel<<<NN * DD / 4 / 256, 256, 0, stream>>>(part_s, dinv, bias, out);
    } else {
        deg_kernel<<<NN / 4, 256, 0, stream>>>(adj, dinv);
        proj_kernel<<<NN / 16, 256, 0, stream>>>(x, w, dinv, h2f);
        agg_kernel<1><<<dim3(NN / 16, 1), 256, 0, stream>>>(adj, h2f, dinv, bias, out);
    }
}

// Round 6
// 422.155 us; speedup vs baseline: 1.0088x; 1.0088x over previous
//
#include <hip/hip_runtime.h>
#include <hip/hip_bf16.h>

#define NN 8192
#define DD 128

typedef __attribute__((ext_vector_type(4))) float f32x4;
typedef __attribute__((ext_vector_type(8))) short s16x8;
typedef __attribute__((ext_vector_type(4))) short s16x4;

__device__ inline short bfbits(float f) {
    // fp32 -> bf16 (RNE) bit pattern
    unsigned u = __builtin_bit_cast(unsigned, f);
    u += 0x7fffu + ((u >> 16) & 1u);
    return (short)(u >> 16);
}

__device__ inline s16x4 cvt4(f32x4 a) {
    s16x4 r;
    r[0] = bfbits(a[0]); r[1] = bfbits(a[1]); r[2] = bfbits(a[2]); r[3] = bfbits(a[3]);
    return r;
}

__device__ inline s16x8 cvt8(f32x4 a, f32x4 b) {
    s16x8 r;
    r[0] = bfbits(a[0]); r[1] = bfbits(a[1]); r[2] = bfbits(a[2]); r[3] = bfbits(a[3]);
    r[4] = bfbits(b[0]); r[5] = bfbits(b[1]); r[6] = bfbits(b[2]); r[7] = bfbits(b[3]);
    return r;
}

// uint8 -> exact bf16 of the integer value (q <= 255 has zero low fp32 mantissa bits)
__device__ inline s16x4 dq4(unsigned w) {
    f32x4 f;
    f[0] = (float)(w & 0xffu);
    f[1] = (float)((w >> 8) & 0xffu);
    f[2] = (float)((w >> 16) & 0xffu);
    f[3] = (float)(w >> 24);
    return cvt4(f);
}

__device__ inline s16x8 dq8(uint2 g) {
    s16x4 lo = dq4(g.x), hi = dq4(g.y);
    s16x8 o;
    o[0] = lo[0]; o[1] = lo[1]; o[2] = lo[2]; o[3] = lo[3];
    o[4] = hi[0]; o[5] = hi[1]; o[6] = hi[2]; o[7] = hi[3];
    return o;
}

#define WST 132  // LDS stride (shorts) for W tile: kills 8-way bank conflicts

// ======== Kernel 1 (prep8): row sums (exact fp32, unchanged numerics) + LINEAR uint8
// copy of adj: q = rint(255*v). Writes are 4 B/lane, 256 B/wave contiguous (this fixes
// R1's scattered-tile-write mistake; the swizzle moves to agg8's LDS-write side).
__global__ __launch_bounds__(256) void prep8_kernel(const float* __restrict__ adj,
                                                    float* __restrict__ dinv,
                                                    unsigned* __restrict__ adjq) {
    const int lane = threadIdx.x & 63;
    const int row  = (blockIdx.x << 2) + (threadIdx.x >> 6);
    const float* r = adj + (size_t)row * NN;
    unsigned* cq   = adjq + (size_t)row * (NN / 4);

    f32x4 s = {0.f, 0.f, 0.f, 0.f};
    #pragma unroll 4
    for (int it = 0; it < 32; ++it) {
        f32x4 v = *(const f32x4*)(r + it * 256 + (lane << 2));
        s += v;
        unsigned q0 = (unsigned)rintf(v[0] * 255.f);
        unsigned q1 = (unsigned)rintf(v[1] * 255.f);
        unsigned q2 = (unsigned)rintf(v[2] * 255.f);
        unsigned q3 = (unsigned)rintf(v[3] * 255.f);
        cq[it * 64 + lane] = q0 | (q1 << 8) | (q2 << 16) | (q3 << 24);
    }
    float sum = s[0] + s[1] + s[2] + s[3];
    #pragma unroll
    for (int off = 32; off; off >>= 1) sum += __shfl_xor(sum, off, 64);
    if (lane == 0) dinv[row] = (sum > 0.f) ? rsqrtf(sum) : 0.f;
}

// ======== Kernel 2 (proj): h2f = dinv[j]*(x@W) in B-fragment order — R0/R4 proven ====
__global__ __launch_bounds__(256) void proj_kernel(const float* __restrict__ x,
                                                   const float* __restrict__ w,
                                                   const float* __restrict__ dinv,
                                                   unsigned short* __restrict__ h2f) {
    __shared__ short lds_w[128 * WST];
    const int tid  = threadIdx.x;
    const int lane = tid & 63;
    const int wave = tid >> 6;
    const int j0   = blockIdx.x << 4;
    const int n0   = wave << 5;
    const int r    = lane & 15;
    const int q    = lane >> 4;

    #pragma unroll
    for (int i = 0; i < 16; ++i) {
        int gi = i * 256 + tid;
        int k  = gi >> 5;
        int n4 = (gi & 31) << 2;
        f32x4 v = *(const f32x4*)(w + (size_t)k * DD + n4);
        *(s16x4*)&lds_w[k * WST + n4] = cvt4(v);
    }
    __syncthreads();

    const float* xp = x + (size_t)(j0 + r) * DD + (q << 3);
    f32x4 acc0 = {0.f, 0.f, 0.f, 0.f};
    f32x4 acc1 = {0.f, 0.f, 0.f, 0.f};

    #pragma unroll
    for (int k = 0; k < DD; k += 32) {
        f32x4 a0 = *(const f32x4*)(xp + k);
        f32x4 a1 = *(const f32x4*)(xp + k + 4);
        s16x8 af = cvt8(a0, a1);
        const int kb = k + (q << 3);
        s16x8 b0, b1;
        #pragma unroll
        for (int jj = 0; jj < 8; ++jj) {
            b0[jj] = lds_w[(kb + jj) * WST + n0 + r];
            b1[jj] = lds_w[(kb + jj) * WST + n0 + 16 + r];
        }
        acc0 = __builtin_amdgcn_mfma_f32_16x16x32_bf16(af, b0, acc0, 0, 0, 0);
        acc1 = __builtin_amdgcn_mfma_f32_16x16x32_bf16(af, b1, acc1, 0, 0, 0);
    }

    #pragma unroll
    for (int rr = 0; rr < 4; ++rr) {
        const int j = j0 + (q << 2) + rr;
        const float dv = dinv[j];
        const int kg = j >> 5, qp = (j >> 3) & 3, jj = j & 7;
        #pragma unroll
        for (int half = 0; half < 2; ++half) {
            const int n = n0 + half * 16 + r;
            const int f = n >> 4;
            const int lanep = qp * 16 + (n & 15);
            const float v = (half ? acc1[rr] : acc0[rr]) * dv;
            h2f[((((size_t)f << 8) + kg) << 6 | lanep) * 8 + jj] = (unsigned short)bfbits(v);
        }
    }
}

// ======== Kernel 3 (agg8): BM=32 agg reading uint8 adjq (4x less A HBM traffic) =======
// MFMA loop, B-path, swizzle geometry byte-identical to R4's proven agg32; only the
// staging changes: 8 B uint8 load per row-chunk -> exact bf16 dequant -> one 16 B
// swizzled ds_write (replaces fp32 load + cvt4 pair). 1/255 folds into reduce4q.
template <int KSPLIT>
__global__ __launch_bounds__(256, 4) void agg8_kernel(const unsigned char* __restrict__ adjq,
                                                      const unsigned short* __restrict__ h2f,
                                                      float* __restrict__ dst) {
    constexpr int KS    = NN / KSPLIT;
    constexpr int TILES = KS / 128;
    __shared__ __align__(16) short lds_a[2][2][16 * 16 * 8];  // [buf][subtile][slot*8]

    const int tid  = threadIdx.x;
    const int lane = tid & 63;
    const int wave = tid >> 6;
    const int r    = lane & 15;
    const int q    = lane >> 4;
    const int m0   = blockIdx.x << 5;
    const int k0   = blockIdx.y * KS;

    // staging: thread -> rows rw (subtile0) and rw+16 (subtile1), 8-elem chunk c8
    const int c8 = tid & 15;
    const int rw = tid >> 4;                      // 0..15
    const int so = ((rw << 4) + (c8 ^ rw)) * 8;   // swizzled slot, 8 shorts (16 B)

    const unsigned char* aq0 = adjq + (size_t)(m0 + rw)      * NN + k0 + (c8 << 3);
    const unsigned char* aq1 = adjq + (size_t)(m0 + 16 + rw) * NN + k0 + (c8 << 3);

    const unsigned short* bb0 = h2f + (((size_t)(wave * 2)     * 256 + (k0 >> 5)) * 64 + lane) * 8;
    const unsigned short* bb1 = h2f + (((size_t)(wave * 2 + 1) * 256 + (k0 >> 5)) * 64 + lane) * 8;

    f32x4 acc00 = {0.f, 0.f, 0.f, 0.f};
    f32x4 acc01 = {0.f, 0.f, 0.f, 0.f};
    f32x4 acc10 = {0.f, 0.f, 0.f, 0.f};
    f32x4 acc11 = {0.f, 0.f, 0.f, 0.f};

    // prologue: stage tile 0
    {
        uint2 ga = *(const uint2*)(aq0);
        uint2 gb = *(const uint2*)(aq1);
        *(s16x8*)&lds_a[0][0][so] = dq8(ga);
        *(s16x8*)&lds_a[0][1][so] = dq8(gb);
    }
    __syncthreads();

    for (int t = 0; t < TILES; ++t) {
        const short* lc0 = lds_a[t & 1][0];
        const short* lc1 = lds_a[t & 1][1];

        // B loads first (L2-resident; MFMA vmcnt waits exclude the A prefetch)
        s16x8 br0[4], br1[4];
        #pragma unroll
        for (int s = 0; s < 4; ++s) {
            br0[s] = *(const s16x8*)(bb0 + (size_t)(t * 4 + s) * 512);
            br1[s] = *(const s16x8*)(bb1 + (size_t)(t * 4 + s) * 512);
        }
        // A prefetch (HBM uint8; consumed only after the MFMAs)
        uint2 ga, gb;
        if (t + 1 < TILES) {
            ga = *(const uint2*)(aq0 + (t + 1) * 128);
            gb = *(const uint2*)(aq1 + (t + 1) * 128);
        }
        #pragma unroll
        for (int s = 0; s < 4; ++s) {
            const int slot = (r << 4) + (((s << 2) + q) ^ r);
            s16x8 afA = *(const s16x8*)(lc0 + slot * 8);
            s16x8 afB = *(const s16x8*)(lc1 + slot * 8);
            acc00 = __builtin_amdgcn_mfma_f32_16x16x32_bf16(afA, br0[s], acc00, 0, 0, 0);
            acc01 = __builtin_amdgcn_mfma_f32_16x16x32_bf16(afA, br1[s], acc01, 0, 0, 0);
            acc10 = __builtin_amdgcn_mfma_f32_16x16x32_bf16(afB, br0[s], acc10, 0, 0, 0);
            acc11 = __builtin_amdgcn_mfma_f32_16x16x32_bf16(afB, br1[s], acc11, 0, 0, 0);
        }
        if (t + 1 < TILES) {
            *(s16x8*)&lds_a[(t + 1) & 1][0][so] = dq8(ga);
            *(s16x8*)&lds_a[(t + 1) & 1][1][so] = dq8(gb);
        }
        __syncthreads();
    }

    float* p = dst + (size_t)blockIdx.y * NN * DD;
    #pragma unroll
    for (int rr = 0; rr < 4; ++rr) {
        const int mA = m0 + (q << 2) + rr;
        const int mB = mA + 16;
        const int n  = (wave << 5) + r;
        p[(size_t)mA * DD + n]      = acc00[rr];
        p[(size_t)mA * DD + n + 16] = acc01[rr];
        p[(size_t)mB * DD + n]      = acc10[rr];
        p[(size_t)mB * DD + n + 16] = acc11[rr];
    }
}

// ======== Kernel 4 (reduce4q): out = (dinv[m]/255)*(p0+p1+p2+p3) + bias ===============
__global__ __launch_bounds__(256) void reduce4q_kernel(const float* __restrict__ part,
                                                       const float* __restrict__ dinv,
                                                       const float* __restrict__ bias,
                                                       float* __restrict__ out) {
    const int idx = blockIdx.x * 256 + threadIdx.x;   // f32x4 index, NN*DD/4 total
    const f32x4 a = ((const f32x4*)part)[idx];
    const f32x4 b = ((const f32x4*)part)[idx + NN * DD / 4];
    const f32x4 c = ((const f32x4*)part)[idx + 2 * (NN * DD / 4)];
    const f32x4 d = ((const f32x4*)part)[idx + 3 * (NN * DD / 4)];
    const float dv = dinv[idx >> 5] * (1.f / 255.f);
    const f32x4 bi = *(const f32x4*)(bias + ((idx & 31) << 2));
    f32x4 s = (a + b) + (c + d);
    f32x4 o;
    o[0] = s[0] * dv + bi[0]; o[1] = s[1] * dv + bi[1];
    o[2] = s[2] * dv + bi[2]; o[3] = s[3] * dv + bi[3];
    ((f32x4*)out)[idx] = o;
}

// ================= FALLBACK kernels (proven R0/R4 paths) ==============================
__global__ __launch_bounds__(256) void deg_kernel(const float* __restrict__ adj,
                                                  float* __restrict__ dinv) {
    const int lane = threadIdx.x & 63;
    const int row  = (blockIdx.x << 2) + (threadIdx.x >> 6);
    const float* r = adj + (size_t)row * NN;
    f32x4 s = {0.f, 0.f, 0.f, 0.f};
    #pragma unroll 4
    for (int it = 0; it < 32; ++it) {
        f32x4 v = *(const f32x4*)(r + it * 256 + (lane << 2));
        s += v;
    }
    float sum = s[0] + s[1] + s[2] + s[3];
    #pragma unroll
    for (int off = 32; off; off >>= 1) sum += __shfl_xor(sum, off, 64);
    if (lane == 0) dinv[row] = (sum > 0.f) ? rsqrtf(sum) : 0.f;
}

template <int KSPLIT>
__global__ __launch_bounds__(256, 4) void agg32_kernel(const float* __restrict__ adj,
                                                       const unsigned short* __restrict__ h2f,
                                                       float* __restrict__ dst) {
    constexpr int KS    = NN / KSPLIT;
    constexpr int TILES = KS / 128;
    __shared__ short lds_a[2][2][16 * 16 * 8];
    const int tid  = threadIdx.x;
    const int lane = tid & 63;
    const int wave = tid >> 6;
    const int r    = lane & 15;
    const int q    = lane >> 4;
    const int m0   = blockIdx.x << 5;
    const int k0   = blockIdx.y * KS;
    const int row0 = tid >> 5;
    const int off0 = (tid & 31) << 2;
    const int cd   = (tid & 31) >> 1;
    const int hh   = tid & 1;
    const int so0  = ((row0 << 4) + (cd ^ row0)) * 8 + hh * 4;
    const int so1  = (((8 + row0) << 4) + (cd ^ (8 + row0))) * 8 + hh * 4;
    const float* ap0 = adj + (size_t)(m0 + row0)      * NN + k0 + off0;
    const float* ap1 = adj + (size_t)(m0 + 8 + row0)  * NN + k0 + off0;
    const float* ap2 = adj + (size_t)(m0 + 16 + row0) * NN + k0 + off0;
    const float* ap3 = adj + (size_t)(m0 + 24 + row0) * NN + k0 + off0;
    const unsigned short* bb0 = h2f + (((size_t)(wave * 2)     * 256 + (k0 >> 5)) * 64 + lane) * 8;
    const unsigned short* bb1 = h2f + (((size_t)(wave * 2 + 1) * 256 + (k0 >> 5)) * 64 + lane) * 8;
    f32x4 acc00 = {0.f, 0.f, 0.f, 0.f};
    f32x4 acc01 = {0.f, 0.f, 0.f, 0.f};
    f32x4 acc10 = {0.f, 0.f, 0.f, 0.f};
    f32x4 acc11 = {0.f, 0.f, 0.f, 0.f};
    {
        f32x4 v0 = *(const f32x4*)(ap0);
        f32x4 v1 = *(const f32x4*)(ap1);
        f32x4 v2 = *(const f32x4*)(ap2);
        f32x4 v3 = *(const f32x4*)(ap3);
        *(s16x4*)&lds_a[0][0][so0] = cvt4(v0);
        *(s16x4*)&lds_a[0][0][so1] = cvt4(v1);
        *(s16x4*)&lds_a[0][1][so0] = cvt4(v2);
        *(s16x4*)&lds_a[0][1][so1] = cvt4(v3);
    }
    __syncthreads();
    for (int t = 0; t < TILES; ++t) {
        const short* lc0 = lds_a[t & 1][0];
        const short* lc1 = lds_a[t & 1][1];
        s16x8 br0[4], br1[4];
        #pragma unroll
        for (int s = 0; s < 4; ++s) {
            br0[s] = *(const s16x8*)(bb0 + (size_t)(t * 4 + s) * 512);
            br1[s] = *(const s16x8*)(bb1 + (size_t)(t * 4 + s) * 512);
        }
        f32x4 v0, v1, v2, v3;
        if (t + 1 < TILES) {
            v0 = *(const f32x4*)(ap0 + (t + 1) * 128);
            v1 = *(const f32x4*)(ap1 + (t + 1) * 128);
            v2 = *(const f32x4*)(ap2 + (t + 1) * 128);
            v3 = *(const f32x4*)(ap3 + (t + 1) * 128);
        }
        #pragma unroll
        for (int s = 0; s < 4; ++s) {
            const int slot = (r << 4) + (((s << 2) + q) ^ r);
            s16x8 afA = *(const s16x8*)(lc0 + slot * 8);
            s16x8 afB = *(const s16x8*)(lc1 + slot * 8);
            acc00 = __builtin_amdgcn_mfma_f32_16x16x32_bf16(afA, br0[s], acc00, 0, 0, 0);
            acc01 = __builtin_amdgcn_mfma_f32_16x16x32_bf16(afA, br1[s], acc01, 0, 0, 0);
            acc10 = __builtin_amdgcn_mfma_f32_16x16x32_bf16(afB, br0[s], acc10, 0, 0, 0);
            acc11 = __builtin_amdgcn_mfma_f32_16x16x32_bf16(afB, br1[s], acc11, 0, 0, 0);
        }
        if (t + 1 < TILES) {
            short* ln0 = (short*)lds_a[(t + 1) & 1][0];
            short* ln1 = (short*)lds_a[(t + 1) & 1][1];
            *(s16x4*)(ln0 + so0) = cvt4(v0);
            *(s16x4*)(ln0 + so1) = cvt4(v1);
            *(s16x4*)(ln1 + so0) = cvt4(v2);
            *(s16x4*)(ln1 + so1) = cvt4(v3);
        }
        __syncthreads();
    }
    float* p = dst + (size_t)blockIdx.y * NN * DD;
    #pragma unroll
    for (int rr = 0; rr < 4; ++rr) {
        const int mA = m0 + (q << 2) + rr;
        const int mB = mA + 16;
        const int n  = (wave << 5) + r;
        p[(size_t)mA * DD + n]      = acc00[rr];
        p[(size_t)mA * DD + n + 16] = acc01[rr];
        p[(size_t)mB * DD + n]      = acc10[rr];
        p[(size_t)mB * DD + n + 16] = acc11[rr];
    }
}

__global__ __launch_bounds__(256) void reduce4_kernel(const float* __restrict__ part,
                                                      const float* __restrict__ dinv,
                                                      const float* __restrict__ bias,
                                                      float* __restrict__ out) {
    const int idx = blockIdx.x * 256 + threadIdx.x;
    const f32x4 a = ((const f32x4*)part)[idx];
    const f32x4 b = ((const f32x4*)part)[idx + NN * DD / 4];
    const f32x4 c = ((const f32x4*)part)[idx + 2 * (NN * DD / 4)];
    const f32x4 d = ((const f32x4*)part)[idx + 3 * (NN * DD / 4)];
    const float dv = dinv[idx >> 5];
    const f32x4 bi = *(const f32x4*)(bias + ((idx & 31) << 2));
    f32x4 s = (a + b) + (c + d);
    f32x4 o;
    o[0] = s[0] * dv + bi[0]; o[1] = s[1] * dv + bi[1];
    o[2] = s[2] * dv + bi[2]; o[3] = s[3] * dv + bi[3];
    ((f32x4*)out)[idx] = o;
}

template <int KSPLIT>
__global__ __launch_bounds__(256, 4) void agg_kernel(const float* __restrict__ adj,
                                                     const unsigned short* __restrict__ h2f,
                                                     const float* __restrict__ dinv,
                                                     const float* __restrict__ bias,
                                                     float* __restrict__ dst) {
    constexpr int KS    = NN / KSPLIT;
    constexpr int TILES = KS / 128;
    __shared__ short lds_a[2][16 * 16 * 8];
    const int tid  = threadIdx.x;
    const int lane = tid & 63;
    const int wave = tid >> 6;
    const int r    = lane & 15;
    const int q    = lane >> 4;
    const int m0   = blockIdx.x << 4;
    const int k0   = blockIdx.y * KS;
    const int row0 = tid >> 5;
    const int off0 = (tid & 31) << 2;
    const int cd   = (tid & 31) >> 1;
    const int hh   = tid & 1;
    const int so0  = ((row0 << 4) + (cd ^ row0)) * 8 + hh * 4;
    const int so1  = (((8 + row0) << 4) + (cd ^ (8 + row0))) * 8 + hh * 4;
    const float* ap0 = adj + (size_t)(m0 + row0) * NN + k0 + off0;
    const float* ap1 = adj + (size_t)(m0 + 8 + row0) * NN + k0 + off0;
    const unsigned short* bb0 = h2f + (((size_t)(wave * 2)     * 256 + (k0 >> 5)) * 64 + lane) * 8;
    const unsigned short* bb1 = h2f + (((size_t)(wave * 2 + 1) * 256 + (k0 >> 5)) * 64 + lane) * 8;
    f32x4 acc0 = {0.f, 0.f, 0.f, 0.f};
    f32x4 acc1 = {0.f, 0.f, 0.f, 0.f};
    {
        f32x4 v0 = *(const f32x4*)(ap0);
        f32x4 v1 = *(const f32x4*)(ap1);
        *(s16x4*)&lds_a[0][so0] = cvt4(v0);
        *(s16x4*)&lds_a[0][so1] = cvt4(v1);
    }
    __syncthreads();
    for (int t = 0; t < TILES; ++t) {
        const short* lcur = lds_a[t & 1];
        short* lnxt = (short*)lds_a[(t + 1) & 1];
        s16x8 br0[4], br1[4];
        #pragma unroll
        for (int s = 0; s < 4; ++s) {
            br0[s] = *(const s16x8*)(bb0 + (size_t)(t * 4 + s) * 512);
            br1[s] = *(const s16x8*)(bb1 + (size_t)(t * 4 + s) * 512);
        }
        f32x4 v0, v1;
        if (t + 1 < TILES) {
            v0 = *(const f32x4*)(ap0 + (t + 1) * 128);
            v1 = *(const f32x4*)(ap1 + (t + 1) * 128);
        }
        #pragma unroll
        for (int s = 0; s < 4; ++s) {
            const int slot = (r << 4) + (((s << 2) + q) ^ r);
            s16x8 af = *(const s16x8*)(lcur + slot * 8);
            acc0 = __builtin_amdgcn_mfma_f32_16x16x32_bf16(af, br0[s], acc0, 0, 0, 0);
            acc1 = __builtin_amdgcn_mfma_f32_16x16x32_bf16(af, br1[s], acc1, 0, 0, 0);
        }
        if (t + 1 < TILES) {
            *(s16x4*)(lnxt + so0) = cvt4(v0);
            *(s16x4*)(lnxt + so1) = cvt4(v1);
        }
        __syncthreads();
    }
    #pragma unroll
    for (int rr = 0; rr < 4; ++rr) {
        const int m = m0 + (q << 2) + rr;
        const int n = (wave << 5) + r;
        if (KSPLIT == 1) {
            const float dv = dinv[m];
            dst[(size_t)m * DD + n]      = acc0[rr] * dv + bias[n];
            dst[(size_t)m * DD + n + 16] = acc1[rr] * dv + bias[n + 16];
        } else {
            float* p = dst + (size_t)blockIdx.y * NN * DD;
            p[(size_t)m * DD + n]      = acc0[rr];
            p[(size_t)m * DD + n + 16] = acc1[rr];
        }
    }
}

__global__ __launch_bounds__(256) void reduce_kernel(const float* __restrict__ part,
                                                     const float* __restrict__ dinv,
                                                     const float* __restrict__ bias,
                                                     float* __restrict__ out) {
    const int idx = blockIdx.x * 256 + threadIdx.x;
    const f32x4 a = ((const f32x4*)part)[idx];
    const f32x4 b = ((const f32x4*)part)[idx + NN * DD / 4];
    const float dv = dinv[idx >> 5];
    const f32x4 bi = *(const f32x4*)(bias + ((idx & 31) << 2));
    f32x4 s = a + b;
    f32x4 o;
    o[0] = s[0] * dv + bi[0]; o[1] = s[1] * dv + bi[1];
    o[2] = s[2] * dv + bi[2]; o[3] = s[3] * dv + bi[3];
    ((f32x4*)out)[idx] = o;
}

extern "C" void kernel_launch(void* const* d_in, const int* in_sizes, int n_in,
                              void* d_out, int out_size, void* d_ws, size_t ws_size,
                              hipStream_t stream) {
    const float* x    = (const float*)d_in[0];   // [8192][128]
    const float* adj  = (const float*)d_in[1];   // [8192][8192]
    const float* w    = (const float*)d_in[2];   // [128][128]
    const float* bias = (const float*)d_in[3];   // [128]
    float* out = (float*)d_out;                  // [8192][128]

    // ws layout: dinv 32KB | h2f 2MB | part 16MB | adjq 64MB
    float* dinv          = (float*)d_ws;
    unsigned short* h2f  = (unsigned short*)((char*)d_ws + 32 * 1024);
    float* part          = (float*)((char*)d_ws + 32 * 1024 + 2 * 1024 * 1024);
    unsigned char* adjq  = (unsigned char*)((char*)d_ws + 32 * 1024 + 18 * 1024 * 1024);
    const size_t base   = 32 * 1024 + 2 * 1024 * 1024;
    const size_t need_q = base + 16 * 1024 * 1024 + (size_t)64 * 1024 * 1024;
    const size_t need4  = base + (size_t)4 * NN * DD * sizeof(float);
    const size_t need2  = base + (size_t)2 * NN * DD * sizeof(float);

    if (ws_size >= need_q) {
        prep8_kernel<<<NN / 4, 256, 0, stream>>>(adj, dinv, (unsigned*)adjq);
        proj_kernel<<<NN / 16, 256, 0, stream>>>(x, w, dinv, h2f);
        agg8_kernel<4><<<dim3(NN / 32, 4), 256, 0, stream>>>(adjq, h2f, part);
        reduce4q_kernel<<<NN * DD / 4 / 256, 256, 0, stream>>>(part, dinv, bias, out);
    } else if (ws_size >= need4) {
        deg_kernel<<<NN / 4, 256, 0, stream>>>(adj, dinv);
        proj_kernel<<<NN / 16, 256, 0, stream>>>(x, w, dinv, h2f);
        agg32_kernel<4><<<dim3(NN / 32, 4), 256, 0, stream>>>(adj, h2f, part);
        reduce4_kernel<<<NN * DD / 4 / 256, 256, 0, stream>>>(part, dinv, bias, out);
    } else if (ws_size >= need2) {
        deg_kernel<<<NN / 4, 256, 0, stream>>>(adj, dinv);
        proj_kernel<<<NN / 16, 256, 0, stream>>>(x, w, dinv, h2f);
        agg_kernel<2><<<dim3(NN / 16, 2), 256, 0, stream>>>(adj, h2f, dinv, bias, part);
        reduce_kernel<<<NN * DD / 4 / 256, 256, 0, stream>>>(part, dinv, bias, out);
    } else {
        deg_kernel<<<NN / 4, 256, 0, stream>>>(adj, dinv);
        proj_kernel<<<NN / 16, 256, 0, stream>>>(x, w, dinv, h2f);
        agg_kernel<1><<<dim3(NN / 16, 1), 256, 0, stream>>>(adj, h2f, dinv, bias, out);
    }
}